// Round 1
// baseline (191.490 us; speedup 1.0000x reference)
//
#include <hip/hip_runtime.h>

typedef _Float16 f16;
typedef _Float16 f16x4 __attribute__((ext_vector_type(4)));
typedef _Float16 f16x8 __attribute__((ext_vector_type(8)));
typedef float f32x4 __attribute__((ext_vector_type(4)));

static __device__ __forceinline__ f32x4 mfma16(f16x8 a, f16x8 b, f32x4 c) {
  return __builtin_amdgcn_mfma_f32_16x16x32_f16(a, b, c, 0, 0, 0);
}

#define BN 2048   // sequence length
#define CC 512    // channels
#define NHD 64    // head dim
#define MROWS 8192 // B*N

// ---------------------------------------------------------------------------
// QKV GEMM: C[m][d] = sum_k X[m][k] * Wqkv[d][k]
// M=8192, D=1536, K=512. Scatter epilogue -> qkv ws (s,b,h,n,hd) f16.
// Q (s==0) scaled by 0.125 = HD^-0.5.
// ---------------------------------------------------------------------------
__global__ __launch_bounds__(256)
void qkv_gemm(const float* __restrict__ X, const float* __restrict__ W,
              f16* __restrict__ qkv) {
  __shared__ __align__(16) f16 As[128][40];
  __shared__ __align__(16) f16 Bs[128][40];
  const int t = threadIdx.x;
  const int lane = t & 63, wave = t >> 6;
  const int wr = wave >> 1, wc = wave & 1;
  const int mt = blockIdx.x / 12, nt = blockIdx.x % 12;
  const int m0 = mt * 128, n0 = nt * 128;
  const int grp = lane >> 4, lid = lane & 15;

  const f32x4 zf = {0.f, 0.f, 0.f, 0.f};
  f32x4 acc[4][4];
#pragma unroll
  for (int i = 0; i < 4; i++)
#pragma unroll
    for (int j = 0; j < 4; j++) acc[i][j] = zf;

  const int r = t >> 1, hh = (t & 1) * 16;
  for (int k0 = 0; k0 < CC; k0 += 32) {
    const float* sa = X + (size_t)(m0 + r) * CC + k0 + hh;
    const float* sb = W + (size_t)(n0 + r) * CC + k0 + hh;
#pragma unroll
    for (int j = 0; j < 4; j++) {
      float4 va = *(const float4*)(sa + 4 * j);
      float4 vb = *(const float4*)(sb + 4 * j);
      f16x4 fa = {(f16)va.x, (f16)va.y, (f16)va.z, (f16)va.w};
      f16x4 fb = {(f16)vb.x, (f16)vb.y, (f16)vb.z, (f16)vb.w};
      *(f16x4*)&As[r][hh + 4 * j] = fa;
      *(f16x4*)&Bs[r][hh + 4 * j] = fb;
    }
    __syncthreads();
    f16x8 af[4], bf[4];
#pragma unroll
    for (int mi = 0; mi < 4; mi++)
      af[mi] = *(const f16x8*)&As[wr * 64 + mi * 16 + lid][grp * 8];
#pragma unroll
    for (int ni = 0; ni < 4; ni++)
      bf[ni] = *(const f16x8*)&Bs[wc * 64 + ni * 16 + lid][grp * 8];
#pragma unroll
    for (int mi = 0; mi < 4; mi++)
#pragma unroll
      for (int ni = 0; ni < 4; ni++)
        acc[mi][ni] = mfma16(af[mi], bf[ni], acc[mi][ni]);
    __syncthreads();
  }
  // epilogue: scatter to (s,b,h,n,hd)
#pragma unroll
  for (int ni = 0; ni < 4; ni++) {
    int d = n0 + wc * 64 + ni * 16 + lid;
    int s = d >> 9;
    int h = (d & 511) >> 6;
    int hd = d & 63;
    float scale = (s == 0) ? 0.125f : 1.0f;
#pragma unroll
    for (int mi = 0; mi < 4; mi++) {
#pragma unroll
      for (int i = 0; i < 4; i++) {
        int row = m0 + wr * 64 + mi * 16 + grp * 4 + i;
        int b = row >> 11, n = row & 2047;
        qkv[((((size_t)s * 4 + b) * 8 + h) * BN + n) * NHD + hd] =
            (f16)(acc[mi][ni][i] * scale);
      }
    }
  }
}

// ---------------------------------------------------------------------------
// Flash attention. Block = 64 q-rows of one (b,h); 4 waves x 16 q-rows.
// Swapped QK^T: S^T = mfma(K_frag, Q_frag) so q = lane&15 (softmax per-column,
// state replicated across the 4 lane-groups). PV: O^T = V^T (LDS) . P (LDS).
// ---------------------------------------------------------------------------
__global__ __launch_bounds__(256)
void attn(const f16* __restrict__ qkv, f16* __restrict__ O) {
  const int bh = blockIdx.x >> 5;  // 0..31 = b*8+h
  const int qb = blockIdx.x & 31;  // q-block (64 rows each)
  const f16* Q = qkv + (size_t)bh * BN * NHD;
  const f16* K = qkv + (size_t)(32 + bh) * BN * NHD;
  const f16* V = qkv + (size_t)(64 + bh) * BN * NHD;
  const int t = threadIdx.x, lane = t & 63, wave = t >> 6;
  const int grp = lane >> 4, qv = lane & 15;
  const int q_row = qb * 64 + wave * 16 + qv;

  __shared__ __align__(16) f16 VT[64][40];     // V^T for current 32-key chunk
  __shared__ __align__(16) f16 P[4][16][40];   // per-wave P (q-major)

  f16x8 qf0 = *(const f16x8*)&Q[(size_t)q_row * NHD + grp * 8];
  f16x8 qf1 = *(const f16x8*)&Q[(size_t)q_row * NHD + 32 + grp * 8];

  const f32x4 zf = {0.f, 0.f, 0.f, 0.f};
  f32x4 acc[4];
#pragma unroll
  for (int i = 0; i < 4; i++) acc[i] = zf;
  float m = -1e30f, l = 0.f;

  for (int k0 = 0; k0 < BN; k0 += 32) {
    // cooperative V^T staging (32 keys x 64 d)
#pragma unroll
    for (int j = 0; j < 2; j++) {
      int task = t * 2 + j;
      int key = task >> 4, d0 = (task & 15) * 4;
      f16x4 v = *(const f16x4*)&V[(size_t)(k0 + key) * NHD + d0];
#pragma unroll
      for (int e = 0; e < 4; e++) VT[d0 + e][key] = v[e];
    }
    // QK^T (S^T tiles: row = key_local, col = q)
    f32x4 st[2];
#pragma unroll
    for (int kt = 0; kt < 2; kt++) {
      const f16* kr = &K[(size_t)(k0 + kt * 16 + qv) * NHD];
      f16x8 kf0 = *(const f16x8*)(kr + grp * 8);
      f16x8 kf1 = *(const f16x8*)(kr + 32 + grp * 8);
      f32x4 z = mfma16(kf0, qf0, zf);
      st[kt] = mfma16(kf1, qf1, z);
    }
    // online softmax, per q = lane&15 (replicated over 4 groups)
    float mt = st[0][0];
#pragma unroll
    for (int kt = 0; kt < 2; kt++)
#pragma unroll
      for (int i = 0; i < 4; i++) mt = fmaxf(mt, st[kt][i]);
    mt = fmaxf(mt, __shfl_xor(mt, 16));
    mt = fmaxf(mt, __shfl_xor(mt, 32));
    float newm = fmaxf(m, mt);
    float f = __expf(m - newm);
    float p[8];
    float ps = 0.f;
#pragma unroll
    for (int kt = 0; kt < 2; kt++)
#pragma unroll
      for (int i = 0; i < 4; i++) {
        float e = __expf(st[kt][i] - newm);
        p[kt * 4 + i] = e;
        ps += e;
      }
    ps += __shfl_xor(ps, 16);
    ps += __shfl_xor(ps, 32);
    l = l * f + ps;
    m = newm;
#pragma unroll
    for (int dt = 0; dt < 4; dt++) acc[dt] *= f;
    // P relayout (q-major) for PV B-operand
#pragma unroll
    for (int kt = 0; kt < 2; kt++)
#pragma unroll
      for (int i = 0; i < 4; i++)
        P[wave][qv][kt * 16 + grp * 4 + i] = (f16)p[kt * 4 + i];
    __syncthreads();
    // PV: O^T[dtile] += V^T . P
    f16x8 pf = *(const f16x8*)&P[wave][qv][grp * 8];
#pragma unroll
    for (int dt = 0; dt < 4; dt++) {
      f16x8 vf = *(const f16x8*)&VT[dt * 16 + qv][grp * 8];
      acc[dt] = mfma16(vf, pf, acc[dt]);
    }
    __syncthreads();
  }
  // epilogue -> O in (B,N,C) layout, f16
  const int b = bh >> 3, h = bh & 7;
  float inv = 1.0f / l;
#pragma unroll
  for (int dt = 0; dt < 4; dt++)
#pragma unroll
    for (int i = 0; i < 4; i++) {
      int d = dt * 16 + grp * 4 + i;
      O[((size_t)(b * BN + q_row)) * CC + h * NHD + d] = (f16)(acc[dt][i] * inv);
    }
}

// ---------------------------------------------------------------------------
// Output projection: out[m][d] = sum_c A[m][c] * Wproj[d][c] + bias[d]
// M=8192, D=512, K=512. A is f16 ws, output f32.
// ---------------------------------------------------------------------------
__global__ __launch_bounds__(256)
void proj_gemm(const f16* __restrict__ A, const float* __restrict__ W,
               const float* __restrict__ bias, float* __restrict__ out) {
  __shared__ __align__(16) f16 As[128][40];
  __shared__ __align__(16) f16 Bs[128][40];
  const int t = threadIdx.x;
  const int lane = t & 63, wave = t >> 6;
  const int wr = wave >> 1, wc = wave & 1;
  const int mt = blockIdx.x >> 2, nt = blockIdx.x & 3;
  const int m0 = mt * 128, n0 = nt * 128;
  const int grp = lane >> 4, lid = lane & 15;

  const f32x4 zf = {0.f, 0.f, 0.f, 0.f};
  f32x4 acc[4][4];
#pragma unroll
  for (int i = 0; i < 4; i++)
#pragma unroll
    for (int j = 0; j < 4; j++) acc[i][j] = zf;

  const int r = t >> 1, hh = (t & 1) * 16;
  for (int k0 = 0; k0 < CC; k0 += 32) {
    const f16* sa = A + (size_t)(m0 + r) * CC + k0 + hh;
    f16x8 a0 = *(const f16x8*)sa;
    f16x8 a1 = *(const f16x8*)(sa + 8);
    *(f16x8*)&As[r][hh] = a0;
    *(f16x8*)&As[r][hh + 8] = a1;
    const float* sb = W + (size_t)(n0 + r) * CC + k0 + hh;
#pragma unroll
    for (int j = 0; j < 4; j++) {
      float4 vb = *(const float4*)(sb + 4 * j);
      f16x4 fb = {(f16)vb.x, (f16)vb.y, (f16)vb.z, (f16)vb.w};
      *(f16x4*)&Bs[r][hh + 4 * j] = fb;
    }
    __syncthreads();
    f16x8 af[4], bf[4];
#pragma unroll
    for (int mi = 0; mi < 4; mi++)
      af[mi] = *(const f16x8*)&As[wr * 64 + mi * 16 + lid][grp * 8];
#pragma unroll
    for (int ni = 0; ni < 4; ni++)
      bf[ni] = *(const f16x8*)&Bs[wc * 64 + ni * 16 + lid][grp * 8];
#pragma unroll
    for (int mi = 0; mi < 4; mi++)
#pragma unroll
      for (int ni = 0; ni < 4; ni++)
        acc[mi][ni] = mfma16(af[mi], bf[ni], acc[mi][ni]);
    __syncthreads();
  }
#pragma unroll
  for (int mi = 0; mi < 4; mi++) {
#pragma unroll
    for (int ni = 0; ni < 4; ni++) {
      int d = n0 + wc * 64 + ni * 16 + lid;
      float bv = bias[d];
#pragma unroll
      for (int i = 0; i < 4; i++) {
        int row = m0 + wr * 64 + mi * 16 + grp * 4 + i;
        out[(size_t)row * CC + d] = acc[mi][ni][i] + bv;
      }
    }
  }
}

extern "C" void kernel_launch(void* const* d_in, const int* in_sizes, int n_in,
                              void* d_out, int out_size, void* d_ws, size_t ws_size,
                              hipStream_t stream) {
  const float* x = (const float*)d_in[0];
  const float* w_qkv = (const float*)d_in[1];
  const float* w_proj = (const float*)d_in[2];
  const float* b_proj = (const float*)d_in[3];
  float* out = (float*)d_out;

  f16* qkv = (f16*)d_ws;                         // 3*8192*512 f16 = 25.2 MB
  f16* Obuf = qkv + (size_t)3 * MROWS * CC;      // 8192*512 f16  =  8.4 MB

  qkv_gemm<<<dim3(64 * 12), dim3(256), 0, stream>>>(x, w_qkv, qkv);
  attn<<<dim3(32 * 32), dim3(256), 0, stream>>>(qkv, Obuf);
  proj_gemm<<<dim3(64 * 4), dim3(256), 0, stream>>>(Obuf, w_proj, b_proj, out);
}